// Round 1
// 598.545 us; speedup vs baseline: 1.0400x; 1.0400x over previous
//
#include <hip/hip_runtime.h>
#include <hip/hip_fp16.h>
#include <math.h>

// B=16, N=16384, C_IN=C_OUT=128, K=9
#define B_ 16
#define N_ 16384
#define C_ 128
#define K_ 9
#define FCONV 1152           // K_*C_
#define G_ 2                 // nodes per block
#define FPAD 1160            // flat row stride in halfs (1152+8): 16B-aligned, stride%32dw==4 -> conflict-free
#define LDS_BYTES (G_ * B_ * FPAD * 2)   // 74240 B dynamic LDS

typedef _Float16 half8 __attribute__((ext_vector_type(8)));
typedef float floatx4 __attribute__((ext_vector_type(4)));

__device__ __forceinline__ float elu_f(float v) {
    // fast ELU: exp(v)-1 for v<0 via v_exp_f32 (abs err ~1e-6)
    return v > 0.f ? v : (__expf(v) - 1.f);
}

// Pre-swizzle W into MFMA b-fragment-major f16 layout in d_ws:
//  conv: frag index ((ot*36 + kc)*64 + lane), 8 halfs each; value = Wc[ot*16 + (lane&15)][kc*32 + (lane>>4)*8 + j]
//  skip: frag index ((ot*4 + kc)*64 + lane);               value = Ws[ot*16 + (lane&15)][kc*32 + (lane>>4)*8 + j]
__global__ void build_wfrag(const float* __restrict__ Wc, const float* __restrict__ Ws,
                            _Float16* __restrict__ WcF, _Float16* __restrict__ WsF) {
    const int i = blockIdx.x * 256 + threadIdx.x;
    if (i < 8 * 36 * 64 * 8) {
        const int j = i & 7, lane = (i >> 3) & 63;
        const int rest = i >> 9;               // ot*36 + kc
        const int kc = rest % 36, ot = rest / 36;
        WcF[i] = (_Float16)Wc[(size_t)(ot * 16 + (lane & 15)) * FCONV + kc * 32 + (lane >> 4) * 8 + j];
    }
    if (i < 8 * 4 * 64 * 8) {
        const int j = i & 7, lane = (i >> 3) & 63;
        const int rest = i >> 9;               // ot*4 + kc
        const int kc = rest & 3, ot = rest >> 2;
        WsF[i] = (_Float16)Ws[(size_t)(ot * 16 + (lane & 15)) * C_ + kc * 32 + (lane >> 4) * 8 + j];
    }
}

template <bool WF16>
__global__ __launch_bounds__(1024, 8) void paiconv_mfma(
    const float* __restrict__ x,      // (B,N,C)
    const int*   __restrict__ idx,    // (N,K)
    const float* __restrict__ P,      // (N,K,K)
    const void*  __restrict__ WcP,    // WF16: fragment-major f16; else fp32 row-major (C_OUT, K*C)
    const float* __restrict__ bc,
    const void*  __restrict__ WsP,    // WF16: fragment-major f16; else fp32 row-major (C_OUT, C)
    const float* __restrict__ bs,
    float*       __restrict__ out)    // (B,N,C_OUT)
{
    extern __shared__ _Float16 flat_s[];     // [G][16][FPAD] f16

    const int tid = threadIdx.x;
    const int n0  = blockIdx.x * G_;

    // ---------------- phase 1: gather + P-mix + ELU -> flat_s (f16) ----------------
    // 1024 threads = (bg 0..7) x (c 0..127); each thread owns batches m = bg*2, bg*2+1.
    // idx/P are wave-uniform -> scalar loads (SGPRs), no LDS staging, no broadcast ds_reads.
    {
        const int c  = tid & (C_ - 1);
        const int bg = tid >> 7;                // 0..7
        #pragma unroll
        for (int g = 0; g < G_; ++g) {
            const int n = n0 + g;
            int id[K_];
            #pragma unroll
            for (int j = 0; j < K_; ++j) id[j] = idx[(size_t)n * K_ + j];   // uniform -> s_load

            // issue all 18 gather loads back-to-back (MLP)
            float v[2][K_];
            #pragma unroll
            for (int i = 0; i < 2; ++i) {
                const int m = bg * 2 + i;
                const float* xb = x + (size_t)m * (N_ * C_) + c;
                #pragma unroll
                for (int j = 0; j < K_; ++j)
                    v[i][j] = ((unsigned)id[j] < (unsigned)N_) ? xb[(size_t)id[j] * C_] : 0.f;
            }

            _Float16* fg = &flat_s[g * (B_ * FPAD)];
            const float* Pn = P + (size_t)n * 81;
            #pragma unroll
            for (int k = 0; k < K_; ++k) {
                float pr[K_];
                #pragma unroll
                for (int j = 0; j < K_; ++j) pr[j] = Pn[k * K_ + j];        // uniform -> s_load
                #pragma unroll
                for (int i = 0; i < 2; ++i) {
                    float s = 0.f;
                    #pragma unroll
                    for (int j = 0; j < K_; ++j) s = fmaf(pr[j], v[i][j], s);
                    fg[(bg * 2 + i) * FPAD + k * C_ + c] = (_Float16)elu_f(s);
                }
            }
        }
    }
    __syncthreads();

    // ---------------- phase 2: MFMA GEMMs ----------------
    // 16 waves = (g 0..1) x (ot 0..7): wave does node n0+g, output cols [ot*16, ot*16+16)
    const int w    = tid >> 6;
    const int lane = tid & 63;
    const int col  = lane & 15;      // a-frag row m / b-frag col o / C-frag col
    const int quad = lane >> 4;      // 0..3
    const int g    = w & 1;
    const int ot   = w >> 1;         // 0..7
    const int o0   = ot * 16;
    const int n    = n0 + g;

    floatx4 accC = (floatx4){0.f, 0.f, 0.f, 0.f};
    floatx4 accS = (floatx4){0.f, 0.f, 0.f, 0.f};

    // skip GEMM first (no LDS dependency): x-row (M=16 x 128) @ Ws^T
    for (int k0 = 0; k0 < C_; k0 += 32) {
        const float* p = x + (size_t)col * (N_ * C_) + (size_t)n * C_ + k0 + quad * 8;
        const float4 x0 = *(const float4*)p;
        const float4 x1 = *(const float4*)(p + 4);
        half8 a = (half8){(_Float16)x0.x, (_Float16)x0.y, (_Float16)x0.z, (_Float16)x0.w,
                          (_Float16)x1.x, (_Float16)x1.y, (_Float16)x1.z, (_Float16)x1.w};
        half8 b;
        if (WF16) {
            b = ((const half8*)WsP)[(ot * 4 + (k0 >> 5)) * 64 + lane];
        } else {
            const float* q = (const float*)WsP + (size_t)(o0 + col) * C_ + k0 + quad * 8;
            const float4 w0 = *(const float4*)q;
            const float4 w1 = *(const float4*)(q + 4);
            b = (half8){(_Float16)w0.x, (_Float16)w0.y, (_Float16)w0.z, (_Float16)w0.w,
                        (_Float16)w1.x, (_Float16)w1.y, (_Float16)w1.z, (_Float16)w1.w};
        }
        accS = __builtin_amdgcn_mfma_f32_16x16x32_f16(a, b, accS, 0, 0, 0);
    }

    // conv GEMM: flat (M=16 x 1152) @ Wc^T -> 16x16 tile
    const _Float16* fg = &flat_s[g * (B_ * FPAD) + col * FPAD];
    for (int k0 = 0; k0 < FCONV; k0 += 32) {
        half8 a = *(const half8*)&fg[k0 + quad * 8];
        half8 b;
        if (WF16) {
            b = ((const half8*)WcP)[(ot * 36 + (k0 >> 5)) * 64 + lane];
        } else {
            const float* q = (const float*)WcP + (size_t)(o0 + col) * FCONV + k0 + quad * 8;
            const float4 w0 = *(const float4*)q;
            const float4 w1 = *(const float4*)(q + 4);
            b = (half8){(_Float16)w0.x, (_Float16)w0.y, (_Float16)w0.z, (_Float16)w0.w,
                        (_Float16)w1.x, (_Float16)w1.y, (_Float16)w1.z, (_Float16)w1.w};
        }
        accC = __builtin_amdgcn_mfma_f32_16x16x32_f16(a, b, accC, 0, 0, 0);
    }

    // ---------------- epilogue: out = elu(conv + bc) + skip + bs ----------------
    const float bcv = bc[o0 + col];
    const float bsv = bs[o0 + col];
    #pragma unroll
    for (int r = 0; r < 4; ++r) {
        const int m = quad * 4 + r;     // C/D: row = (lane>>4)*4 + reg
        const float z = elu_f(accC[r] + bcv);
        // write-once stream: nt store keeps `out` from evicting the gather-hot x in L2/LLC
        __builtin_nontemporal_store(z + accS[r] + bsv,
                                    &out[((size_t)m * N_ + n) * C_ + o0 + col]);
    }
}

extern "C" void kernel_launch(void* const* d_in, const int* in_sizes, int n_in,
                              void* d_out, int out_size, void* d_ws, size_t ws_size,
                              hipStream_t stream) {
    const float* x   = (const float*)d_in[0];
    const int*   idx = (const int*)  d_in[1];
    const float* P   = (const float*)d_in[2];
    const float* Wc  = (const float*)d_in[3];
    const float* bc  = (const float*)d_in[4];
    const float* Ws  = (const float*)d_in[5];
    const float* bs  = (const float*)d_in[6];
    float* out = (float*)d_out;

    const size_t wc_halfs = (size_t)8 * 36 * 64 * 8;   // 147456
    const size_t ws_halfs = (size_t)8 * 4 * 64 * 8;    // 16384
    const size_t need = (wc_halfs + ws_halfs) * sizeof(_Float16);

    if (ws_size >= need) {
        _Float16* WcF = (_Float16*)d_ws;
        _Float16* WsF = WcF + wc_halfs;
        build_wfrag<<<dim3(576), dim3(256), 0, stream>>>(Wc, Ws, WcF, WsF);
        hipFuncSetAttribute((const void*)paiconv_mfma<true>,
                            hipFuncAttributeMaxDynamicSharedMemorySize, LDS_BYTES);
        paiconv_mfma<true><<<dim3(N_ / G_), dim3(1024), LDS_BYTES, stream>>>(
            x, idx, P, WcF, bc, WsF, bs, out);
    } else {
        hipFuncSetAttribute((const void*)paiconv_mfma<false>,
                            hipFuncAttributeMaxDynamicSharedMemorySize, LDS_BYTES);
        paiconv_mfma<false><<<dim3(N_ / G_), dim3(1024), LDS_BYTES, stream>>>(
            x, idx, P, Wc, bc, Ws, bs, out);
    }
}